// Round 6
// baseline (158.097 us; speedup 1.0000x reference)
//
#include <hip/hip_runtime.h>
#include <hip/hip_bf16.h>
#include <math.h>

#define NFEAT 17
#define DN 20
#define OCH 32
#define H1 500
#define H2 60

// ws float offsets
#define OFF_D      0         // 8192*20 = 163840
#define OFF_MOMP   163840    // 256 blocks * 232 = 59392 partial moments
#define OFF_ACOEF  223232    // 32
#define OFF_COEFC  223264    // 32
#define OFF_WQ     223296    // 288
#define OFF_WP     223584    // 288
#define OFF_U      223872    // 500*20 = 10000
#define OFF_CST    233872    // 512
#define OFF_W2H    234384    // 2*500*32 = 32000 (padded w2 transpose halves)
// total 266384 floats ~= 1.07 MB

// ---------- K1: fused g-gather + distribute + per-block moment partials ----------
// 2 threads per node (one per element gather, split distribute f-range).
// Tail blocks: w2 -> padded transposed halves w2h, and wq/wp tap tables.
#define TB1 128
__global__ __launch_bounds__(TB1) void k_gd(const float* __restrict__ oe,
                                            const int* __restrict__ nei,
                                            const int* __restrict__ eai,
                                            const float* __restrict__ w2,
                                            const float* __restrict__ convw,
                                            float* __restrict__ dmat,
                                            float* __restrict__ momp,
                                            float* __restrict__ w2h,
                                            float* __restrict__ wq,
                                            float* __restrict__ wp, int n_node) {
  int nbd = (n_node + 63) / 64;
  int tid = threadIdx.x;
  if ((int)blockIdx.x >= nbd) {
    int tb = blockIdx.x - nbd;
    if (tb < 32) {
      for (int idx = tb * TB1 + tid; idx < 2 * H1 * 32; idx += 32 * TB1) {
        int h = idx / (H1 * 32);
        int r = idx - h * (H1 * 32);
        int o = r >> 5, j = r & 31;
        w2h[idx] = (j < 30) ? w2[(size_t)(h * 30 + j) * H1 + o] : 0.f;
      }
    } else if (tid < OCH) {
      int c = tid;
      float w[3][3];
#pragma unroll
      for (int p = 0; p < 3; ++p)
#pragma unroll
        for (int q = 0; q < 3; ++q) w[p][q] = convw[c * 9 + p * 3 + q];
#pragma unroll
      for (int p = 0; p < 3; ++p) {
        wq[(c * 3 + p) * 3 + 0] = w[p][1] + w[p][2];
        wq[(c * 3 + p) * 3 + 1] = w[p][0] + w[p][1] + w[p][2];
        wq[(c * 3 + p) * 3 + 2] = w[p][0] + w[p][1];
      }
#pragma unroll
      for (int q = 0; q < 3; ++q) {
        wp[(c * 3 + q) * 3 + 0] = w[1][q] + w[2][q];
        wp[(c * 3 + q) * 3 + 1] = w[0][q] + w[1][q] + w[2][q];
        wp[(c * 3 + q) * 3 + 2] = w[0][q] + w[1][q];
      }
    }
    return;
  }

  __shared__ float dls[64][21];
  int nl = tid >> 1, half = tid & 1;
  int n = blockIdx.x * 64 + nl;

  // gather one element's g-row
  float v[NFEAT];
#pragma unroll
  for (int f = 0; f < NFEAT; ++f) v[f] = 0.f;
  if (n < n_node) {
    int e = eai[(size_t)n * 2 + half];
    float a4[NFEAT];
#pragma unroll
    for (int f = 0; f < NFEAT; ++f) a4[f] = 0.f;
#pragma unroll
    for (int m = 0; m < 4; ++m) {
      int at = nei[(size_t)e * 4 + m];
      const float* row = oe + (size_t)at * NFEAT;
#pragma unroll
      for (int f = 0; f < NFEAT; ++f) a4[f] += row[f];
    }
    float nrm = 0.f;
#pragma unroll
    for (int f = 0; f < NFEAT; ++f) { float t = a4[f] * 0.25f; a4[f] = t; nrm += t * t; }
    float inv = 1.0f / sqrtf(nrm);
#pragma unroll
    for (int f = 0; f < NFEAT; ++f) v[f] = a4[f] * inv;
  }
  float h[NFEAT];
#pragma unroll
  for (int f = 0; f < NFEAT; ++f) h[f] = v[f] + __shfl_xor(v[f], 1);

  // distribute: this thread covers f in [f0,f1)
  const float step = 50.0f / 19.0f;
  const float inv2 = 1.0f / (2.0f * 0.3f * 0.3f);
  float s[DN];
#pragma unroll
  for (int k = 0; k < DN; ++k) s[k] = 0.f;
  int f0 = half ? 9 : 0, f1 = half ? NFEAT : 9;
  for (int f = f0; f < f1; ++f) {
    float y = h[f];
    if (!(y > 0.0f && y < 110.0f)) continue;
    float ek[DN];
    float m = 0.f;
#pragma unroll
    for (int k = 0; k < DN; ++k) {
      float t2 = step * (float)k - y;
      ek[k] = __expf(-t2 * t2 * inv2);
      m = fmaxf(m, ek[k]);
    }
    if (m > 0.f) {
      float im = 1.0f / m;
#pragma unroll
      for (int k = 0; k < DN; ++k) s[k] += ek[k] * im;
    }
  }
#pragma unroll
  for (int k = 0; k < DN; ++k) s[k] += __shfl_xor(s[k], 1);
  float smax = 0.f;
#pragma unroll
  for (int k = 0; k < DN; ++k) smax = fmaxf(smax, s[k]);
  float ism = (smax > 0.f) ? 1.0f / smax : 1.0f;

#pragma unroll
  for (int k = 0; k < 10; ++k) {
    float dv = s[half * 10 + k] * ism;
    dls[nl][half * 10 + k] = dv;
    if (n < n_node) dmat[(size_t)n * DN + half * 10 + k] = dv;
  }
  __syncthreads();

  // per-block moment partials: 210 tri P + 20 sums
  for (int u = tid; u < 230; u += TB1) {
    float acc = 0.f;
    if (u < 210) {
      int a = 0, rem = u;
      while (rem >= DN - a) { rem -= DN - a; ++a; }
      int b = a + rem;
      for (int l = 0; l < 64; ++l) acc += dls[l][a] * dls[l][b];
    } else {
      int a = u - 210;
      for (int l = 0; l < 64; ++l) acc += dls[l][a];
    }
    momp[(size_t)blockIdx.x * 232 + u] = acc;
  }
}

// ---------- K2: reduce moment partials + BN stats (one block per channel) ----------
__global__ __launch_bounds__(512) void k_coef(const float* __restrict__ momp, int nbd,
                                              const float* __restrict__ convw,
                                              const float* __restrict__ convb,
                                              const float* __restrict__ gamma,
                                              const float* __restrict__ beta,
                                              float* __restrict__ acoef,
                                              float* __restrict__ coefc, int n_node) {
  int c = blockIdx.x;
  int tid = threadIdx.x;
  __shared__ float P[DN * DN];
  __shared__ float S[DN];
  __shared__ float red1[512], red2[512];
  if (tid < 230) {
    float acc = 0.f;
    for (int b = 0; b < nbd; ++b) acc += momp[(size_t)b * 232 + tid];
    if (tid < 210) {
      int a = 0, rem = tid;
      while (rem >= DN - a) { rem -= DN - a; ++a; }
      int b = a + rem;
      P[a * DN + b] = acc; P[b * DN + a] = acc;
    } else {
      S[tid - 210] = acc;
    }
  }
  __syncthreads();

  float w[3][3];
#pragma unroll
  for (int p = 0; p < 3; ++p)
#pragma unroll
    for (int q = 0; q < 3; ++q) w[p][q] = convw[c * 9 + p * 3 + q];
  float b_c = convb[c];

  float ssq = 0.f, sm = 0.f;
  if (tid < DN * DN) {
    int i = tid / DN, j = tid % DN;
    bool iv[3] = { i > 0, true, i < DN - 1 };
    bool jv[3] = { j > 0, true, j < DN - 1 };
    int idxs[6]; float cf[6]; int nt = 0;
#pragma unroll
    for (int p = 0; p < 3; ++p) if (iv[p]) {
      float cc = 0.f;
#pragma unroll
      for (int q = 0; q < 3; ++q) if (jv[q]) cc += w[p][q];
      idxs[nt] = i - 1 + p; cf[nt] = cc; ++nt;
    }
#pragma unroll
    for (int q = 0; q < 3; ++q) if (jv[q]) {
      float cc = 0.f;
#pragma unroll
      for (int p = 0; p < 3; ++p) if (iv[p]) cc += w[p][q];
      idxs[nt] = j - 1 + q; cf[nt] = cc; ++nt;
    }
    float q1 = 0.f, q2 = 0.f;
    for (int u = 0; u < nt; ++u) {
      q2 += cf[u] * S[idxs[u]];
      for (int v2 = 0; v2 < nt; ++v2)
        q1 += cf[u] * cf[v2] * P[idxs[u] * DN + idxs[v2]];
    }
    ssq = q1 + 2.f * b_c * q2;
    sm = q2;
  }
  red1[tid] = ssq; red2[tid] = sm;
  __syncthreads();
  for (int st = 256; st > 0; st >>= 1) {
    if (tid < st) { red1[tid] += red1[tid + st]; red2[tid] += red2[tid + st]; }
    __syncthreads();
  }
  if (tid == 0) {
    float Nt = (float)n_node * 400.f;
    float S1 = red2[0] + Nt * b_c;
    float S2 = red1[0] + Nt * b_c * b_c;
    float mu = S1 / Nt;
    float var = S2 / Nt - mu * mu;
    float a = gamma[c] / sqrtf(var + 1e-5f);
    acoef[c] = a;
    coefc[c] = a * (b_c - mu) + beta[c];
  }
}

// ---------- K3: collapse conv+BN+FC1 weights: U[o,a], Cst[o] ----------
__global__ __launch_bounds__(512) void k_buildU(const float* __restrict__ w1,
                                                const float* __restrict__ b1,
                                                const float* __restrict__ acoef,
                                                const float* __restrict__ coefc,
                                                const float* __restrict__ wq,
                                                const float* __restrict__ wp,
                                                float* __restrict__ U,
                                                float* __restrict__ Cst) {
  int o = blockIdx.x;
  int tid = threadIdx.x;
  __shared__ float Ul[DN];
  __shared__ float red[512];
  __shared__ float swq[288], swp[288], sac[OCH], scc[OCH];
  for (int idx = tid; idx < 288; idx += 512) { swq[idx] = wq[idx]; swp[idx] = wp[idx]; }
  if (tid < OCH) { sac[tid] = acoef[tid]; scc[tid] = coefc[tid]; }
  if (tid < DN) Ul[tid] = 0.f;
  __syncthreads();

  float cacc = 0.f;
  bool act = tid < DN * DN;
  int i = tid / DN, j = tid % DN;
  if (act) {
    int icls = (i == 0) ? 0 : ((i == DN - 1) ? 2 : 1);
    int jcls = (j == 0) ? 0 : ((j == DN - 1) ? 2 : 1);
    const float* w1o = w1 + (size_t)o * (OCH * DN * DN) + i * DN + j;
    float uI = 0.f, uJ = 0.f, uIm = 0.f, uIp = 0.f, uJm = 0.f, uJp = 0.f;
    for (int c = 0; c < OCH; ++c) {
      float v = w1o[c * (DN * DN)];
      float a = sac[c];
      cacc += scc[c] * v;
      float av = a * v;
      uI += v;
      uJ += v;
      uIm += av * swq[(c * 3 + 0) * 3 + jcls];
      uI  += av * swq[(c * 3 + 1) * 3 + jcls];
      uIp += av * swq[(c * 3 + 2) * 3 + jcls];
      uJm += av * swp[(c * 3 + 0) * 3 + icls];
      uJ  += av * swp[(c * 3 + 1) * 3 + icls];
      uJp += av * swp[(c * 3 + 2) * 3 + icls];
    }
    atomicAdd(&Ul[i], uI);
    atomicAdd(&Ul[j], uJ);
    if (i > 0)      atomicAdd(&Ul[i - 1], uIm);
    if (i < DN - 1) atomicAdd(&Ul[i + 1], uIp);
    if (j > 0)      atomicAdd(&Ul[j - 1], uJm);
    if (j < DN - 1) atomicAdd(&Ul[j + 1], uJp);
  }
  red[tid] = cacc;
  __syncthreads();
  for (int st = 256; st > 0; st >>= 1) {
    if (tid < st) red[tid] += red[tid + st];
    __syncthreads();
  }
  if (tid == 0) Cst[o] = b1[o] + red[0];
  if (tid < DN) U[o * DN + tid] = Ul[tid];
}

// ---------- K4: fused FC1(rank-20)+ReLU+FC2 ----------
// 1024 threads = 16 waves; 32 nodes/block; o-loop strided across waves.
// lane: n32 = lane&31 (node), khalf = lane>>5 (30 of 60 outputs each).
// 16 waves/CU = 4/SIMD for latency hiding; VGPR capped at 128 by launch_bounds.
#define KFT 1024
__global__ __launch_bounds__(KFT, 4) void k_final(const float* __restrict__ dmat,
                                                  const float* __restrict__ U,
                                                  const float* __restrict__ Cst,
                                                  const float* __restrict__ w2h,
                                                  const float* __restrict__ b2,
                                                  float* __restrict__ out, int n_node) {
  __shared__ float lout[32 * 65];
  int tid = threadIdx.x;
  int wave = tid >> 6, lane = tid & 63;
  int n32 = lane & 31, khalf = lane >> 5;
  int n0 = blockIdx.x * 32;
  int n = n0 + n32;

  float d0[DN];
#pragma unroll
  for (int a = 0; a < DN; ++a) d0[a] = 0.f;
  if (n < n_node) {
    const float4* dr = (const float4*)(dmat + (size_t)n * DN);
#pragma unroll
    for (int q = 0; q < 5; ++q) {
      float4 t = dr[q];
      d0[q * 4 + 0] = t.x; d0[q * 4 + 1] = t.y;
      d0[q * 4 + 2] = t.z; d0[q * 4 + 3] = t.w;
    }
  }
  for (int idx = tid; idx < 32 * 65; idx += KFT) lout[idx] = 0.f;
  __syncthreads();

  float acc[30];
#pragma unroll
  for (int j = 0; j < 30; ++j) acc[j] = 0.f;

  const float* wb = w2h + (size_t)khalf * (H1 * 32);
  // o-loop strided across the 16 waves: each wave handles ~31 o's
  for (int o = wave; o < H1; o += 16) {
    float4 uv[5], wv[8];
    const float4* ur = (const float4*)(U + (size_t)o * DN);
#pragma unroll
    for (int q = 0; q < 5; ++q) uv[q] = ur[q];
    const float4* wr = (const float4*)(wb + (size_t)o * 32);
#pragma unroll
    for (int q = 0; q < 8; ++q) wv[q] = wr[q];
    float z = Cst[o];
#pragma unroll
    for (int q = 0; q < 5; ++q)
      z += uv[q].x * d0[q * 4 + 0] + uv[q].y * d0[q * 4 + 1] +
           uv[q].z * d0[q * 4 + 2] + uv[q].w * d0[q * 4 + 3];
    z = fmaxf(z, 0.f);
#pragma unroll
    for (int q = 0; q < 8; ++q) {
      int j = q * 4;
      if (j + 0 < 30) acc[j + 0] += wv[q].x * z;
      if (j + 1 < 30) acc[j + 1] += wv[q].y * z;
      if (j + 2 < 30) acc[j + 2] += wv[q].z * z;
      if (j + 3 < 30) acc[j + 3] += wv[q].w * z;
    }
  }
#pragma unroll
  for (int j = 0; j < 30; ++j)
    atomicAdd(&lout[n32 * 65 + khalf * 30 + j], acc[j]);
  __syncthreads();

  int rem = n_node - n0; if (rem > 32) rem = 32;
  int lim = rem * H2;
  for (int idx = tid; idx < lim; idx += KFT) {
    int nn = idx / H2, k = idx - nn * H2;
    out[(size_t)n0 * H2 + idx] = lout[nn * 65 + k] + b2[k];
  }
}

extern "C" void kernel_launch(void* const* d_in, const int* in_sizes, int n_in,
                              void* d_out, int out_size, void* d_ws, size_t ws_size,
                              hipStream_t stream) {
  const float* oe    = (const float*)d_in[0];
  const int*   nei   = (const int*)d_in[1];
  const int*   eai   = (const int*)d_in[2];
  const float* convw = (const float*)d_in[3];
  const float* convb = (const float*)d_in[4];
  const float* gamma = (const float*)d_in[5];
  const float* beta  = (const float*)d_in[6];
  const float* w1    = (const float*)d_in[7];
  const float* b1    = (const float*)d_in[8];
  const float* w2    = (const float*)d_in[9];
  const float* b2    = (const float*)d_in[10];
  float* out = (float*)d_out;
  float* ws  = (float*)d_ws;

  int n_node = in_sizes[2] / 2;

  float* dmat  = ws + OFF_D;
  float* momp  = ws + OFF_MOMP;
  float* acoef = ws + OFF_ACOEF;
  float* coefc = ws + OFF_COEFC;
  float* wq    = ws + OFF_WQ;
  float* wp    = ws + OFF_WP;
  float* U     = ws + OFF_U;
  float* Cst   = ws + OFF_CST;
  float* w2h   = ws + OFF_W2H;

  int nbd = (n_node + 63) / 64;
  k_gd<<<nbd + 33, TB1, 0, stream>>>(oe, nei, eai, w2, convw,
                                     dmat, momp, w2h, wq, wp, n_node);
  k_coef<<<OCH, 512, 0, stream>>>(momp, nbd, convw, convb, gamma, beta,
                                  acoef, coefc, n_node);
  k_buildU<<<H1, 512, 0, stream>>>(w1, b1, acoef, coefc, wq, wp, U, Cst);
  k_final<<<(n_node + 31) / 32, KFT, 0, stream>>>(dmat, U, Cst, w2h, b2, out, n_node);
}

// Round 7
// 100.474 us; speedup vs baseline: 1.5735x; 1.5735x over previous
//
#include <hip/hip_runtime.h>
#include <hip/hip_bf16.h>
#include <math.h>

#define NFEAT 17
#define DN 20
#define OCH 32
#define H1 500
#define H2 60

// ws float offsets
#define OFF_D      0         // 8192*20 = 163840
#define OFF_MOMP   163840    // 256 blocks * 232 = 59392 partial moments
#define OFF_ACOEF  223232    // 32
#define OFF_COEFC  223264    // 32
#define OFF_WQ     223296    // 288
#define OFF_WP     223584    // 288
#define OFF_U      223872    // 500*20 = 10000
#define OFF_CST    233872    // 512
#define OFF_W2T    234384    // 500*64 = 32000 (padded w2 transpose [o][64])
// total 266384 floats ~= 1.07 MB

// ---------- K1: fused g-gather + distribute + per-block moment partials ----------
#define TB1 128
__global__ __launch_bounds__(TB1) void k_gd(const float* __restrict__ oe,
                                            const int* __restrict__ nei,
                                            const int* __restrict__ eai,
                                            const float* __restrict__ w2,
                                            const float* __restrict__ convw,
                                            float* __restrict__ dmat,
                                            float* __restrict__ momp,
                                            float* __restrict__ w2t,
                                            float* __restrict__ wq,
                                            float* __restrict__ wp, int n_node) {
  int nbd = (n_node + 63) / 64;
  int tid = threadIdx.x;
  if ((int)blockIdx.x >= nbd) {
    int tb = blockIdx.x - nbd;
    if (tb < 32) {
      // transpose w2 (60x500) -> w2t [500][64], zero-padded cols 60..63
      for (int idx = tb * TB1 + tid; idx < H1 * 64; idx += 32 * TB1) {
        int o = idx >> 6, j = idx & 63;
        w2t[idx] = (j < H2) ? w2[(size_t)j * H1 + o] : 0.f;
      }
    } else if (tid < OCH) {
      int c = tid;
      float w[3][3];
#pragma unroll
      for (int p = 0; p < 3; ++p)
#pragma unroll
        for (int q = 0; q < 3; ++q) w[p][q] = convw[c * 9 + p * 3 + q];
#pragma unroll
      for (int p = 0; p < 3; ++p) {
        wq[(c * 3 + p) * 3 + 0] = w[p][1] + w[p][2];
        wq[(c * 3 + p) * 3 + 1] = w[p][0] + w[p][1] + w[p][2];
        wq[(c * 3 + p) * 3 + 2] = w[p][0] + w[p][1];
      }
#pragma unroll
      for (int q = 0; q < 3; ++q) {
        wp[(c * 3 + q) * 3 + 0] = w[1][q] + w[2][q];
        wp[(c * 3 + q) * 3 + 1] = w[0][q] + w[1][q] + w[2][q];
        wp[(c * 3 + q) * 3 + 2] = w[0][q] + w[1][q];
      }
    }
    return;
  }

  __shared__ float dls[64][21];
  int nl = tid >> 1, half = tid & 1;
  int n = blockIdx.x * 64 + nl;

  float v[NFEAT];
#pragma unroll
  for (int f = 0; f < NFEAT; ++f) v[f] = 0.f;
  if (n < n_node) {
    int e = eai[(size_t)n * 2 + half];
    float a4[NFEAT];
#pragma unroll
    for (int f = 0; f < NFEAT; ++f) a4[f] = 0.f;
#pragma unroll
    for (int m = 0; m < 4; ++m) {
      int at = nei[(size_t)e * 4 + m];
      const float* row = oe + (size_t)at * NFEAT;
#pragma unroll
      for (int f = 0; f < NFEAT; ++f) a4[f] += row[f];
    }
    float nrm = 0.f;
#pragma unroll
    for (int f = 0; f < NFEAT; ++f) { float t = a4[f] * 0.25f; a4[f] = t; nrm += t * t; }
    float inv = 1.0f / sqrtf(nrm);
#pragma unroll
    for (int f = 0; f < NFEAT; ++f) v[f] = a4[f] * inv;
  }
  float h[NFEAT];
#pragma unroll
  for (int f = 0; f < NFEAT; ++f) h[f] = v[f] + __shfl_xor(v[f], 1);

  const float step = 50.0f / 19.0f;
  const float inv2 = 1.0f / (2.0f * 0.3f * 0.3f);
  float s[DN];
#pragma unroll
  for (int k = 0; k < DN; ++k) s[k] = 0.f;
  int f0 = half ? 9 : 0, f1 = half ? NFEAT : 9;
  for (int f = f0; f < f1; ++f) {
    float y = h[f];
    if (!(y > 0.0f && y < 110.0f)) continue;
    float ek[DN];
    float m = 0.f;
#pragma unroll
    for (int k = 0; k < DN; ++k) {
      float t2 = step * (float)k - y;
      ek[k] = __expf(-t2 * t2 * inv2);
      m = fmaxf(m, ek[k]);
    }
    if (m > 0.f) {
      float im = 1.0f / m;
#pragma unroll
      for (int k = 0; k < DN; ++k) s[k] += ek[k] * im;
    }
  }
#pragma unroll
  for (int k = 0; k < DN; ++k) s[k] += __shfl_xor(s[k], 1);
  float smax = 0.f;
#pragma unroll
  for (int k = 0; k < DN; ++k) smax = fmaxf(smax, s[k]);
  float ism = (smax > 0.f) ? 1.0f / smax : 1.0f;

#pragma unroll
  for (int k = 0; k < 10; ++k) {
    float dv = s[half * 10 + k] * ism;
    dls[nl][half * 10 + k] = dv;
    if (n < n_node) dmat[(size_t)n * DN + half * 10 + k] = dv;
  }
  __syncthreads();

  for (int u = tid; u < 230; u += TB1) {
    float acc = 0.f;
    if (u < 210) {
      int a = 0, rem = u;
      while (rem >= DN - a) { rem -= DN - a; ++a; }
      int b = a + rem;
      for (int l = 0; l < 64; ++l) acc += dls[l][a] * dls[l][b];
    } else {
      int a = u - 210;
      for (int l = 0; l < 64; ++l) acc += dls[l][a];
    }
    momp[(size_t)blockIdx.x * 232 + u] = acc;
  }
}

// ---------- K2: reduce moment partials + BN stats (one block per channel) ----------
__global__ __launch_bounds__(512) void k_coef(const float* __restrict__ momp, int nbd,
                                              const float* __restrict__ convw,
                                              const float* __restrict__ convb,
                                              const float* __restrict__ gamma,
                                              const float* __restrict__ beta,
                                              float* __restrict__ acoef,
                                              float* __restrict__ coefc, int n_node) {
  int c = blockIdx.x;
  int tid = threadIdx.x;
  __shared__ float P[DN * DN];
  __shared__ float S[DN];
  __shared__ float red1[512], red2[512];
  if (tid < 230) {
    float acc = 0.f;
    for (int b = 0; b < nbd; ++b) acc += momp[(size_t)b * 232 + tid];
    if (tid < 210) {
      int a = 0, rem = tid;
      while (rem >= DN - a) { rem -= DN - a; ++a; }
      int b = a + rem;
      P[a * DN + b] = acc; P[b * DN + a] = acc;
    } else {
      S[tid - 210] = acc;
    }
  }
  __syncthreads();

  float w[3][3];
#pragma unroll
  for (int p = 0; p < 3; ++p)
#pragma unroll
    for (int q = 0; q < 3; ++q) w[p][q] = convw[c * 9 + p * 3 + q];
  float b_c = convb[c];

  float ssq = 0.f, sm = 0.f;
  if (tid < DN * DN) {
    int i = tid / DN, j = tid % DN;
    bool iv[3] = { i > 0, true, i < DN - 1 };
    bool jv[3] = { j > 0, true, j < DN - 1 };
    int idxs[6]; float cf[6]; int nt = 0;
#pragma unroll
    for (int p = 0; p < 3; ++p) if (iv[p]) {
      float cc = 0.f;
#pragma unroll
      for (int q = 0; q < 3; ++q) if (jv[q]) cc += w[p][q];
      idxs[nt] = i - 1 + p; cf[nt] = cc; ++nt;
    }
#pragma unroll
    for (int q = 0; q < 3; ++q) if (jv[q]) {
      float cc = 0.f;
#pragma unroll
      for (int p = 0; p < 3; ++p) if (iv[p]) cc += w[p][q];
      idxs[nt] = j - 1 + q; cf[nt] = cc; ++nt;
    }
    float q1 = 0.f, q2 = 0.f;
    for (int u = 0; u < nt; ++u) {
      q2 += cf[u] * S[idxs[u]];
      for (int v2 = 0; v2 < nt; ++v2)
        q1 += cf[u] * cf[v2] * P[idxs[u] * DN + idxs[v2]];
    }
    ssq = q1 + 2.f * b_c * q2;
    sm = q2;
  }
  red1[tid] = ssq; red2[tid] = sm;
  __syncthreads();
  for (int st = 256; st > 0; st >>= 1) {
    if (tid < st) { red1[tid] += red1[tid + st]; red2[tid] += red2[tid + st]; }
    __syncthreads();
  }
  if (tid == 0) {
    float Nt = (float)n_node * 400.f;
    float S1 = red2[0] + Nt * b_c;
    float S2 = red1[0] + Nt * b_c * b_c;
    float mu = S1 / Nt;
    float var = S2 / Nt - mu * mu;
    float a = gamma[c] / sqrtf(var + 1e-5f);
    acoef[c] = a;
    coefc[c] = a * (b_c - mu) + beta[c];
  }
}

// ---------- K3: collapse conv+BN+FC1 weights: U[o,a], Cst[o] ----------
__global__ __launch_bounds__(512) void k_buildU(const float* __restrict__ w1,
                                                const float* __restrict__ b1,
                                                const float* __restrict__ acoef,
                                                const float* __restrict__ coefc,
                                                const float* __restrict__ wq,
                                                const float* __restrict__ wp,
                                                float* __restrict__ U,
                                                float* __restrict__ Cst) {
  int o = blockIdx.x;
  int tid = threadIdx.x;
  __shared__ float Ul[DN];
  __shared__ float red[512];
  __shared__ float swq[288], swp[288], sac[OCH], scc[OCH];
  for (int idx = tid; idx < 288; idx += 512) { swq[idx] = wq[idx]; swp[idx] = wp[idx]; }
  if (tid < OCH) { sac[tid] = acoef[tid]; scc[tid] = coefc[tid]; }
  if (tid < DN) Ul[tid] = 0.f;
  __syncthreads();

  float cacc = 0.f;
  bool act = tid < DN * DN;
  int i = tid / DN, j = tid % DN;
  if (act) {
    int icls = (i == 0) ? 0 : ((i == DN - 1) ? 2 : 1);
    int jcls = (j == 0) ? 0 : ((j == DN - 1) ? 2 : 1);
    const float* w1o = w1 + (size_t)o * (OCH * DN * DN) + i * DN + j;
    float uI = 0.f, uJ = 0.f, uIm = 0.f, uIp = 0.f, uJm = 0.f, uJp = 0.f;
    for (int c = 0; c < OCH; ++c) {
      float v = w1o[c * (DN * DN)];
      float a = sac[c];
      cacc += scc[c] * v;
      float av = a * v;
      uI += v;
      uJ += v;
      uIm += av * swq[(c * 3 + 0) * 3 + jcls];
      uI  += av * swq[(c * 3 + 1) * 3 + jcls];
      uIp += av * swq[(c * 3 + 2) * 3 + jcls];
      uJm += av * swp[(c * 3 + 0) * 3 + icls];
      uJ  += av * swp[(c * 3 + 1) * 3 + icls];
      uJp += av * swp[(c * 3 + 2) * 3 + icls];
    }
    atomicAdd(&Ul[i], uI);
    atomicAdd(&Ul[j], uJ);
    if (i > 0)      atomicAdd(&Ul[i - 1], uIm);
    if (i < DN - 1) atomicAdd(&Ul[i + 1], uIp);
    if (j > 0)      atomicAdd(&Ul[j - 1], uJm);
    if (j < DN - 1) atomicAdd(&Ul[j + 1], uJp);
  }
  red[tid] = cacc;
  __syncthreads();
  for (int st = 256; st > 0; st >>= 1) {
    if (tid < st) red[tid] += red[tid + st];
    __syncthreads();
  }
  if (tid == 0) Cst[o] = b1[o] + red[0];
  if (tid < DN) U[o * DN + tid] = Ul[tid];
}

// ---------- K4: fused FC1(rank-20)+ReLU+FC2 — two-phase LDS tile ----------
// block = 256 thr, 16 nodes, K=500 in 4 chunks of 125.
// phase1: h1[k][node]=relu(Cst+U·d) (d0[20] in regs). phase2: acc[4] (1 node x 4 outs).
// Per-thread live state <= ~28 regs -> no spill. Grid 512 = 2 blocks/CU.
#define NTN 16
#define KC 125
__global__ __launch_bounds__(256) void k_final(const float* __restrict__ dmat,
                                               const float* __restrict__ U,
                                               const float* __restrict__ Cst,
                                               const float* __restrict__ w2t,
                                               const float* __restrict__ b2,
                                               float* __restrict__ out, int n_node) {
  __shared__ float h1[KC][NTN + 1];
  __shared__ float w2s[KC][64];
  int tid = threadIdx.x;
  int n0 = blockIdx.x * NTN;
  int p1node = tid & 15, p1kq = tid >> 4;       // phase-1 identity
  int wave = tid >> 6, lane = tid & 63;         // phase-2 identity
  int nl2 = wave * 4 + (lane & 3);
  int og = lane >> 2;

  // d0 for phase-1 node (16x thread redundancy, L1-served)
  float d0[DN];
#pragma unroll
  for (int a = 0; a < DN; ++a) d0[a] = 0.f;
  if (n0 + p1node < n_node) {
    const float4* dr = (const float4*)(dmat + (size_t)(n0 + p1node) * DN);
#pragma unroll
    for (int q = 0; q < 5; ++q) {
      float4 t = dr[q];
      d0[q * 4 + 0] = t.x; d0[q * 4 + 1] = t.y;
      d0[q * 4 + 2] = t.z; d0[q * 4 + 3] = t.w;
    }
  }

  float acc[4] = {0.f, 0.f, 0.f, 0.f};

  for (int c = 0; c < 4; ++c) {
    int k0 = c * KC;
    __syncthreads();  // previous phase-2 done before overwriting LDS
    // stage w2 chunk: [125][64] floats, coalesced float4
    {
      const float4* src = (const float4*)(w2t + (size_t)k0 * 64);
      float4* dst = (float4*)&w2s[0][0];
      for (int idx = tid; idx < KC * 16; idx += 256) dst[idx] = src[idx];
    }
    // phase 1: h1 chunk
    for (int k = p1kq; k < KC; k += 16) {
      const float4* ur = (const float4*)(U + (size_t)(k0 + k) * DN);
      float z = Cst[k0 + k];
#pragma unroll
      for (int q = 0; q < 5; ++q) {
        float4 u4 = ur[q];
        z += u4.x * d0[q * 4 + 0] + u4.y * d0[q * 4 + 1] +
             u4.z * d0[q * 4 + 2] + u4.w * d0[q * 4 + 3];
      }
      h1[k][p1node] = fmaxf(z, 0.f);
    }
    __syncthreads();
    // phase 2: acc += h1 * w2s
#pragma unroll 5
    for (int k = 0; k < KC; ++k) {
      float hv = h1[k][nl2];
      float4 wv = *(const float4*)&w2s[k][og * 4];
      acc[0] += hv * wv.x;
      acc[1] += hv * wv.y;
      acc[2] += hv * wv.z;
      acc[3] += hv * wv.w;
    }
  }

  int n = n0 + nl2;
  if (n < n_node) {
#pragma unroll
    for (int j = 0; j < 4; ++j) {
      int o = og * 4 + j;
      if (o < H2) out[(size_t)n * H2 + o] = acc[j] + b2[o];
    }
  }
}

extern "C" void kernel_launch(void* const* d_in, const int* in_sizes, int n_in,
                              void* d_out, int out_size, void* d_ws, size_t ws_size,
                              hipStream_t stream) {
  const float* oe    = (const float*)d_in[0];
  const int*   nei   = (const int*)d_in[1];
  const int*   eai   = (const int*)d_in[2];
  const float* convw = (const float*)d_in[3];
  const float* convb = (const float*)d_in[4];
  const float* gamma = (const float*)d_in[5];
  const float* beta  = (const float*)d_in[6];
  const float* w1    = (const float*)d_in[7];
  const float* b1    = (const float*)d_in[8];
  const float* w2    = (const float*)d_in[9];
  const float* b2    = (const float*)d_in[10];
  float* out = (float*)d_out;
  float* ws  = (float*)d_ws;

  int n_node = in_sizes[2] / 2;

  float* dmat  = ws + OFF_D;
  float* momp  = ws + OFF_MOMP;
  float* acoef = ws + OFF_ACOEF;
  float* coefc = ws + OFF_COEFC;
  float* wq    = ws + OFF_WQ;
  float* wp    = ws + OFF_WP;
  float* U     = ws + OFF_U;
  float* Cst   = ws + OFF_CST;
  float* w2t   = ws + OFF_W2T;

  int nbd = (n_node + 63) / 64;
  k_gd<<<nbd + 33, TB1, 0, stream>>>(oe, nei, eai, w2, convw,
                                     dmat, momp, w2t, wq, wp, n_node);
  k_coef<<<OCH, 512, 0, stream>>>(momp, nbd, convw, convb, gamma, beta,
                                  acoef, coefc, n_node);
  k_buildU<<<H1, 512, 0, stream>>>(w1, b1, acoef, coefc, wq, wp, U, Cst);
  k_final<<<(n_node + NTN - 1) / NTN, 256, 0, stream>>>(dmat, U, Cst, w2t, b2, out, n_node);
}

// Round 8
// 94.095 us; speedup vs baseline: 1.6802x; 1.0678x over previous
//
#include <hip/hip_runtime.h>
#include <hip/hip_bf16.h>
#include <math.h>

#define NFEAT 17
#define DN 20
#define OCH 32
#define H1 500
#define H2 60

// ws float offsets
#define OFF_D      0         // 8192*20 = 163840
#define OFF_MOMP   163840    // 128 blocks * 232
#define OFF_ACOEF  223232    // 32
#define OFF_COEFC  223264    // 32
#define OFF_WQ     223296    // 288
#define OFF_WP     223584    // 288
#define OFF_U      223872    // 500*20
#define OFF_CST    233872    // 512
#define OFF_W2T    234384    // 500*64 (padded w2 transpose [o][64])

// ---------- K1: fused g-gather + distribute + per-block moment partials ----------
#define TB1 128
__global__ __launch_bounds__(TB1) void k_gd(const float* __restrict__ oe,
                                            const int* __restrict__ nei,
                                            const int* __restrict__ eai,
                                            const float* __restrict__ w2,
                                            const float* __restrict__ convw,
                                            float* __restrict__ dmat,
                                            float* __restrict__ momp,
                                            float* __restrict__ w2t,
                                            float* __restrict__ wq,
                                            float* __restrict__ wp, int n_node) {
  int nbd = (n_node + 63) / 64;
  int tid = threadIdx.x;
  if ((int)blockIdx.x >= nbd) {
    int tb = blockIdx.x - nbd;
    if (tb < 32) {
      // transpose w2 (60x500) -> w2t [500][64], zero-padded cols 60..63
      for (int idx = tb * TB1 + tid; idx < H1 * 64; idx += 32 * TB1) {
        int o = idx >> 6, j = idx & 63;
        w2t[idx] = (j < H2) ? w2[(size_t)j * H1 + o] : 0.f;
      }
    } else if (tid < OCH) {
      int c = tid;
      float w[3][3];
#pragma unroll
      for (int p = 0; p < 3; ++p)
#pragma unroll
        for (int q = 0; q < 3; ++q) w[p][q] = convw[c * 9 + p * 3 + q];
#pragma unroll
      for (int p = 0; p < 3; ++p) {
        wq[(c * 3 + p) * 3 + 0] = w[p][1] + w[p][2];
        wq[(c * 3 + p) * 3 + 1] = w[p][0] + w[p][1] + w[p][2];
        wq[(c * 3 + p) * 3 + 2] = w[p][0] + w[p][1];
      }
#pragma unroll
      for (int q = 0; q < 3; ++q) {
        wp[(c * 3 + q) * 3 + 0] = w[1][q] + w[2][q];
        wp[(c * 3 + q) * 3 + 1] = w[0][q] + w[1][q] + w[2][q];
        wp[(c * 3 + q) * 3 + 2] = w[0][q] + w[1][q];
      }
    }
    return;
  }

  __shared__ float dls[64][21];
  int nl = tid >> 1, half = tid & 1;
  int n = blockIdx.x * 64 + nl;

  float v[NFEAT];
#pragma unroll
  for (int f = 0; f < NFEAT; ++f) v[f] = 0.f;
  if (n < n_node) {
    int e = eai[(size_t)n * 2 + half];
    float a4[NFEAT];
#pragma unroll
    for (int f = 0; f < NFEAT; ++f) a4[f] = 0.f;
#pragma unroll
    for (int m = 0; m < 4; ++m) {
      int at = nei[(size_t)e * 4 + m];
      const float* row = oe + (size_t)at * NFEAT;
#pragma unroll
      for (int f = 0; f < NFEAT; ++f) a4[f] += row[f];
    }
    float nrm = 0.f;
#pragma unroll
    for (int f = 0; f < NFEAT; ++f) { float t = a4[f] * 0.25f; a4[f] = t; nrm += t * t; }
    float inv = 1.0f / sqrtf(nrm);
#pragma unroll
    for (int f = 0; f < NFEAT; ++f) v[f] = a4[f] * inv;
  }
  float h[NFEAT];
#pragma unroll
  for (int f = 0; f < NFEAT; ++f) h[f] = v[f] + __shfl_xor(v[f], 1);

  const float step = 50.0f / 19.0f;
  const float inv2 = 1.0f / (2.0f * 0.3f * 0.3f);
  float s[DN];
#pragma unroll
  for (int k = 0; k < DN; ++k) s[k] = 0.f;
  int f0 = half ? 9 : 0, f1 = half ? NFEAT : 9;
  for (int f = f0; f < f1; ++f) {
    float y = h[f];
    if (!(y > 0.0f && y < 110.0f)) continue;
    float ek[DN];
    float m = 0.f;
#pragma unroll
    for (int k = 0; k < DN; ++k) {
      float t2 = step * (float)k - y;
      ek[k] = __expf(-t2 * t2 * inv2);
      m = fmaxf(m, ek[k]);
    }
    if (m > 0.f) {
      float im = 1.0f / m;
#pragma unroll
      for (int k = 0; k < DN; ++k) s[k] += ek[k] * im;
    }
  }
#pragma unroll
  for (int k = 0; k < DN; ++k) s[k] += __shfl_xor(s[k], 1);
  float smax = 0.f;
#pragma unroll
  for (int k = 0; k < DN; ++k) smax = fmaxf(smax, s[k]);
  float ism = (smax > 0.f) ? 1.0f / smax : 1.0f;

#pragma unroll
  for (int k = 0; k < 10; ++k) {
    float dv = s[half * 10 + k] * ism;
    dls[nl][half * 10 + k] = dv;
    if (n < n_node) dmat[(size_t)n * DN + half * 10 + k] = dv;
  }
  __syncthreads();

  for (int u = tid; u < 230; u += TB1) {
    float acc = 0.f;
    if (u < 210) {
      int a = 0, rem = u;
      while (rem >= DN - a) { rem -= DN - a; ++a; }
      int b = a + rem;
      for (int l = 0; l < 64; ++l) acc += dls[l][a] * dls[l][b];
    } else {
      int a = u - 210;
      for (int l = 0; l < 64; ++l) acc += dls[l][a];
    }
    momp[(size_t)blockIdx.x * 232 + u] = acc;
  }
}

// ---------- K2: reduce moment partials + BN stats (one block per channel) ----------
__global__ __launch_bounds__(512) void k_coef(const float* __restrict__ momp, int nbd,
                                              const float* __restrict__ convw,
                                              const float* __restrict__ convb,
                                              const float* __restrict__ gamma,
                                              const float* __restrict__ beta,
                                              float* __restrict__ acoef,
                                              float* __restrict__ coefc, int n_node) {
  int c = blockIdx.x;
  int tid = threadIdx.x;
  __shared__ float P[DN * DN];
  __shared__ float S[DN];
  __shared__ float red1[512], red2[512];
  if (tid < 230) {
    float acc = 0.f;
    for (int b = 0; b < nbd; ++b) acc += momp[(size_t)b * 232 + tid];
    if (tid < 210) {
      int a = 0, rem = tid;
      while (rem >= DN - a) { rem -= DN - a; ++a; }
      int b = a + rem;
      P[a * DN + b] = acc; P[b * DN + a] = acc;
    } else {
      S[tid - 210] = acc;
    }
  }
  __syncthreads();

  float w[3][3];
#pragma unroll
  for (int p = 0; p < 3; ++p)
#pragma unroll
    for (int q = 0; q < 3; ++q) w[p][q] = convw[c * 9 + p * 3 + q];
  float b_c = convb[c];

  float ssq = 0.f, sm = 0.f;
  if (tid < DN * DN) {
    int i = tid / DN, j = tid % DN;
    bool iv[3] = { i > 0, true, i < DN - 1 };
    bool jv[3] = { j > 0, true, j < DN - 1 };
    int idxs[6]; float cf[6]; int nt = 0;
#pragma unroll
    for (int p = 0; p < 3; ++p) if (iv[p]) {
      float cc = 0.f;
#pragma unroll
      for (int q = 0; q < 3; ++q) if (jv[q]) cc += w[p][q];
      idxs[nt] = i - 1 + p; cf[nt] = cc; ++nt;
    }
#pragma unroll
    for (int q = 0; q < 3; ++q) if (jv[q]) {
      float cc = 0.f;
#pragma unroll
      for (int p = 0; p < 3; ++p) if (iv[p]) cc += w[p][q];
      idxs[nt] = j - 1 + q; cf[nt] = cc; ++nt;
    }
    float q1 = 0.f, q2 = 0.f;
    for (int u = 0; u < nt; ++u) {
      q2 += cf[u] * S[idxs[u]];
      for (int v2 = 0; v2 < nt; ++v2)
        q1 += cf[u] * cf[v2] * P[idxs[u] * DN + idxs[v2]];
    }
    ssq = q1 + 2.f * b_c * q2;
    sm = q2;
  }
  red1[tid] = ssq; red2[tid] = sm;
  __syncthreads();
  for (int st = 256; st > 0; st >>= 1) {
    if (tid < st) { red1[tid] += red1[tid + st]; red2[tid] += red2[tid + st]; }
    __syncthreads();
  }
  if (tid == 0) {
    float Nt = (float)n_node * 400.f;
    float S1 = red2[0] + Nt * b_c;
    float S2 = red1[0] + Nt * b_c * b_c;
    float mu = S1 / Nt;
    float var = S2 / Nt - mu * mu;
    float a = gamma[c] / sqrtf(var + 1e-5f);
    acoef[c] = a;
    coefc[c] = a * (b_c - mu) + beta[c];
  }
}

// ---------- K3: collapse conv+BN+FC1 weights via separable row/col stats ----------
// No LDS atomics: row pass (c,i) + col pass (c,j) -> 20-thread gather.
__global__ __launch_bounds__(512) void k_buildU(const float* __restrict__ w1,
                                                const float* __restrict__ b1,
                                                const float* __restrict__ acoef,
                                                const float* __restrict__ coefc,
                                                const float* __restrict__ wq,
                                                const float* __restrict__ wp,
                                                float* __restrict__ U,
                                                float* __restrict__ Cst) {
  int o = blockIdx.x;
  int tid = threadIdx.x;
  __shared__ float rowRS[OCH][DN], rowRW[OCH][3][DN];
  __shared__ float colCS[OCH][DN], colCW[OCH][3][DN];
  __shared__ float swq[288], swp[288], sac[OCH], scc[OCH];
  __shared__ float red[OCH];
  for (int idx = tid; idx < 288; idx += 512) { swq[idx] = wq[idx]; swp[idx] = wp[idx]; }
  if (tid < OCH) { sac[tid] = acoef[tid]; scc[tid] = coefc[tid]; }
  __syncthreads();

  const float* wbase = w1 + (size_t)o * (OCH * DN * DN);

  // row pass: per (c,i) compute plain sum + swq-weighted sums over j
  for (int pair = tid; pair < OCH * DN; pair += 512) {
    int c = pair / DN, i = pair - c * DN;
    const float* r = wbase + c * (DN * DN) + i * DN;
    float rs = 0.f, r0 = 0.f, r1 = 0.f, r2 = 0.f;
#pragma unroll
    for (int j = 0; j < DN; ++j) {
      float vv = r[j];
      int jc = (j == 0) ? 0 : ((j == DN - 1) ? 2 : 1);
      rs += vv;
      r0 += vv * swq[(c * 3 + 0) * 3 + jc];
      r1 += vv * swq[(c * 3 + 1) * 3 + jc];
      r2 += vv * swq[(c * 3 + 2) * 3 + jc];
    }
    rowRS[c][i] = rs;
    rowRW[c][0][i] = r0; rowRW[c][1][i] = r1; rowRW[c][2][i] = r2;
  }
  // col pass: per (c,j) compute plain sum + swp-weighted sums over i
  for (int pair = tid; pair < OCH * DN; pair += 512) {
    int c = pair / DN, j = pair - c * DN;
    const float* base = wbase + c * (DN * DN) + j;
    float cs = 0.f, c0 = 0.f, c1 = 0.f, c2 = 0.f;
#pragma unroll
    for (int i = 0; i < DN; ++i) {
      float vv = base[i * DN];
      int ic = (i == 0) ? 0 : ((i == DN - 1) ? 2 : 1);
      cs += vv;
      c0 += vv * swp[(c * 3 + 0) * 3 + ic];
      c1 += vv * swp[(c * 3 + 1) * 3 + ic];
      c2 += vv * swp[(c * 3 + 2) * 3 + ic];
    }
    colCS[c][j] = cs;
    colCW[c][0][j] = c0; colCW[c][1][j] = c1; colCW[c][2][j] = c2;
  }
  __syncthreads();

  if (tid < DN) {
    int a = tid;
    float u = 0.f;
#pragma unroll
    for (int c = 0; c < OCH; ++c) {
      float plain = rowRS[c][a] + colCS[c][a];
      float m = rowRW[c][1][a] + colCW[c][1][a];
      if (a < DN - 1) m += rowRW[c][0][a + 1] + colCW[c][0][a + 1];
      if (a > 0)      m += rowRW[c][2][a - 1] + colCW[c][2][a - 1];
      u += plain + sac[c] * m;
    }
    U[o * DN + a] = u;
  } else if (tid >= 64 && tid < 64 + OCH) {
    int c = tid - 64;
    float s = 0.f;
#pragma unroll
    for (int i = 0; i < DN; ++i) s += rowRS[c][i];
    red[c] = scc[c] * s;
  }
  __syncthreads();
  if (tid == 0) {
    float s = 0.f;
#pragma unroll
    for (int c = 0; c < OCH; ++c) s += red[c];
    Cst[o] = b1[o] + s;
  }
}

// ---------- K4: fused FC1(rank-20)+ReLU+FC2, node-quad phase-2 ----------
// 16 nodes/block, 512 blocks (2/CU). Phase1: h1s[500][20] in LDS (one pass).
// Phase2: thread = (wave k-slice of 125, node-quad q, out-group og): per k one
// ds_read_b128 (4 h values) + one global float4 of w2t (L2 broadcast) -> 16 FMA.
// acc = 16 statically-indexed scalars (no spill). Partials combined via LDS.
#define NTN 16
__global__ __launch_bounds__(256, 4) void k_final(const float* __restrict__ dmat,
                                                  const float* __restrict__ U,
                                                  const float* __restrict__ Cst,
                                                  const float* __restrict__ w2t,
                                                  const float* __restrict__ b2,
                                                  float* __restrict__ out, int n_node) {
  __shared__ float h1s[H1][20];        // 40 KB, rows 80B -> float4-aligned
  __shared__ float pacc[4][NTN][64];   // 16 KB
  int tid = threadIdx.x;
  int n0 = blockIdx.x * NTN;

  // ---- phase 1: h1s[k][node] = relu(Cst[k] + U[k]·d) ----
  {
    int node = tid & 15, kq = tid >> 4;
    float d0[DN];
#pragma unroll
    for (int a = 0; a < DN; ++a) d0[a] = 0.f;
    if (n0 + node < n_node) {
      const float4* dr = (const float4*)(dmat + (size_t)(n0 + node) * DN);
#pragma unroll
      for (int q = 0; q < 5; ++q) {
        float4 t = dr[q];
        d0[q * 4 + 0] = t.x; d0[q * 4 + 1] = t.y;
        d0[q * 4 + 2] = t.z; d0[q * 4 + 3] = t.w;
      }
    }
    for (int k = kq; k < H1; k += 16) {
      const float4* ur = (const float4*)(U + (size_t)k * DN);
      float z = Cst[k];
#pragma unroll
      for (int q = 0; q < 5; ++q) {
        float4 u4 = ur[q];
        z += u4.x * d0[q * 4 + 0] + u4.y * d0[q * 4 + 1] +
             u4.z * d0[q * 4 + 2] + u4.w * d0[q * 4 + 3];
      }
      h1s[k][node] = fmaxf(z, 0.f);
    }
  }
  __syncthreads();

  // ---- phase 2 ----
  {
    int w = tid >> 6;
    int lane = tid & 63;
    int q = lane >> 4;          // node quad: nodes q*4..q*4+3
    int og = lane & 15;         // outs og*4..og*4+3
    float a0x = 0.f, a0y = 0.f, a0z = 0.f, a0w = 0.f;
    float a1x = 0.f, a1y = 0.f, a1z = 0.f, a1w = 0.f;
    float a2x = 0.f, a2y = 0.f, a2z = 0.f, a2w = 0.f;
    float a3x = 0.f, a3y = 0.f, a3z = 0.f, a3w = 0.f;
    int k0 = w * 125, k1 = k0 + 125;
    for (int k = k0; k < k1; ++k) {
      float4 hv = *(const float4*)&h1s[k][q * 4];
      float4 wv = *(const float4*)(w2t + (size_t)k * 64 + og * 4);
      a0x += hv.x * wv.x; a0y += hv.x * wv.y; a0z += hv.x * wv.z; a0w += hv.x * wv.w;
      a1x += hv.y * wv.x; a1y += hv.y * wv.y; a1z += hv.y * wv.z; a1w += hv.y * wv.w;
      a2x += hv.z * wv.x; a2y += hv.z * wv.y; a2z += hv.z * wv.z; a2w += hv.z * wv.w;
      a3x += hv.w * wv.x; a3y += hv.w * wv.y; a3z += hv.w * wv.z; a3w += hv.w * wv.w;
    }
    float4* p0 = (float4*)&pacc[w][q * 4 + 0][og * 4];
    float4* p1 = (float4*)&pacc[w][q * 4 + 1][og * 4];
    float4* p2 = (float4*)&pacc[w][q * 4 + 2][og * 4];
    float4* p3 = (float4*)&pacc[w][q * 4 + 3][og * 4];
    *p0 = make_float4(a0x, a0y, a0z, a0w);
    *p1 = make_float4(a1x, a1y, a1z, a1w);
    *p2 = make_float4(a2x, a2y, a2z, a2w);
    *p3 = make_float4(a3x, a3y, a3z, a3w);
  }
  __syncthreads();

  // ---- combine 4 k-slice partials + bias + store ----
  for (int idx = tid; idx < NTN * H2; idx += 256) {
    int n = idx / H2, o = idx - n * H2;
    float vv = pacc[0][n][o] + pacc[1][n][o] + pacc[2][n][o] + pacc[3][n][o] + b2[o];
    if (n0 + n < n_node) out[(size_t)(n0 + n) * H2 + o] = vv;
  }
}

extern "C" void kernel_launch(void* const* d_in, const int* in_sizes, int n_in,
                              void* d_out, int out_size, void* d_ws, size_t ws_size,
                              hipStream_t stream) {
  const float* oe    = (const float*)d_in[0];
  const int*   nei   = (const int*)d_in[1];
  const int*   eai   = (const int*)d_in[2];
  const float* convw = (const float*)d_in[3];
  const float* convb = (const float*)d_in[4];
  const float* gamma = (const float*)d_in[5];
  const float* beta  = (const float*)d_in[6];
  const float* w1    = (const float*)d_in[7];
  const float* b1    = (const float*)d_in[8];
  const float* w2    = (const float*)d_in[9];
  const float* b2    = (const float*)d_in[10];
  float* out = (float*)d_out;
  float* ws  = (float*)d_ws;

  int n_node = in_sizes[2] / 2;

  float* dmat  = ws + OFF_D;
  float* momp  = ws + OFF_MOMP;
  float* acoef = ws + OFF_ACOEF;
  float* coefc = ws + OFF_COEFC;
  float* wq    = ws + OFF_WQ;
  float* wp    = ws + OFF_WP;
  float* U     = ws + OFF_U;
  float* Cst   = ws + OFF_CST;
  float* w2t   = ws + OFF_W2T;

  int nbd = (n_node + 63) / 64;
  k_gd<<<nbd + 33, TB1, 0, stream>>>(oe, nei, eai, w2, convw,
                                     dmat, momp, w2t, wq, wp, n_node);
  k_coef<<<OCH, 512, 0, stream>>>(momp, nbd, convw, convb, gamma, beta,
                                  acoef, coefc, n_node);
  k_buildU<<<H1, 512, 0, stream>>>(w1, b1, acoef, coefc, wq, wp, U, Cst);
  k_final<<<(n_node + NTN - 1) / NTN, 256, 0, stream>>>(dmat, U, Cst, w2t, b2, out, n_node);
}

// Round 9
// 68.596 us; speedup vs baseline: 2.3048x; 1.3717x over previous
//
#include <hip/hip_runtime.h>
#include <hip/hip_bf16.h>
#include <math.h>

#define NFEAT 17
#define DN 20
#define OCH 32
#define H1 500
#define H2 60

// ws float offsets
#define OFF_D      0         // 8192*20 = 163840
#define OFF_MOMP   163840    // transposed: [u<232][block<256] = 59392
#define OFF_ACOEF  223232    // 32
#define OFF_COEFC  223264    // 32
#define OFF_WQ     223296    // 288
#define OFF_WP     223584    // 288
#define OFF_U      223872    // 500*20
#define OFF_CST    233872    // 512
#define OFF_W2T    234384    // 500*64 (padded w2 transpose [o][64])

#define NBW 256  // momp block-stride (capacity)

// ---------- K1: fused g-gather + distribute + per-block moment partials ----------
#define TB1 128
__global__ __launch_bounds__(TB1) void k_gd(const float* __restrict__ oe,
                                            const int* __restrict__ nei,
                                            const int* __restrict__ eai,
                                            const float* __restrict__ w2,
                                            const float* __restrict__ convw,
                                            float* __restrict__ dmat,
                                            float* __restrict__ momp,
                                            float* __restrict__ w2t,
                                            float* __restrict__ wq,
                                            float* __restrict__ wp, int n_node) {
  int nbd = (n_node + 63) / 64;
  int tid = threadIdx.x;
  if ((int)blockIdx.x >= nbd) {
    int tb = blockIdx.x - nbd;
    if (tb < 32) {
      // transpose w2 (60x500) -> w2t [500][64], zero-padded cols 60..63
      for (int idx = tb * TB1 + tid; idx < H1 * 64; idx += 32 * TB1) {
        int o = idx >> 6, j = idx & 63;
        w2t[idx] = (j < H2) ? w2[(size_t)j * H1 + o] : 0.f;
      }
    } else if (tid < OCH) {
      int c = tid;
      float w[3][3];
#pragma unroll
      for (int p = 0; p < 3; ++p)
#pragma unroll
        for (int q = 0; q < 3; ++q) w[p][q] = convw[c * 9 + p * 3 + q];
#pragma unroll
      for (int p = 0; p < 3; ++p) {
        wq[(c * 3 + p) * 3 + 0] = w[p][1] + w[p][2];
        wq[(c * 3 + p) * 3 + 1] = w[p][0] + w[p][1] + w[p][2];
        wq[(c * 3 + p) * 3 + 2] = w[p][0] + w[p][1];
      }
#pragma unroll
      for (int q = 0; q < 3; ++q) {
        wp[(c * 3 + q) * 3 + 0] = w[1][q] + w[2][q];
        wp[(c * 3 + q) * 3 + 1] = w[0][q] + w[1][q] + w[2][q];
        wp[(c * 3 + q) * 3 + 2] = w[0][q] + w[1][q];
      }
    }
    return;
  }

  __shared__ float dls[64][21];
  int nl = tid >> 1, half = tid & 1;
  int n = blockIdx.x * 64 + nl;

  float v[NFEAT];
#pragma unroll
  for (int f = 0; f < NFEAT; ++f) v[f] = 0.f;
  if (n < n_node) {
    int e = eai[(size_t)n * 2 + half];
    float a4[NFEAT];
#pragma unroll
    for (int f = 0; f < NFEAT; ++f) a4[f] = 0.f;
#pragma unroll
    for (int m = 0; m < 4; ++m) {
      int at = nei[(size_t)e * 4 + m];
      const float* row = oe + (size_t)at * NFEAT;
#pragma unroll
      for (int f = 0; f < NFEAT; ++f) a4[f] += row[f];
    }
    float nrm = 0.f;
#pragma unroll
    for (int f = 0; f < NFEAT; ++f) { float t = a4[f] * 0.25f; a4[f] = t; nrm += t * t; }
    float inv = 1.0f / sqrtf(nrm);
#pragma unroll
    for (int f = 0; f < NFEAT; ++f) v[f] = a4[f] * inv;
  }
  float h[NFEAT];
#pragma unroll
  for (int f = 0; f < NFEAT; ++f) h[f] = v[f] + __shfl_xor(v[f], 1);

  const float step = 50.0f / 19.0f;
  const float inv2 = 1.0f / (2.0f * 0.3f * 0.3f);
  float s[DN];
#pragma unroll
  for (int k = 0; k < DN; ++k) s[k] = 0.f;
  int f0 = half ? 9 : 0, f1 = half ? NFEAT : 9;
  for (int f = f0; f < f1; ++f) {
    float y = h[f];
    if (!(y > 0.0f && y < 110.0f)) continue;
    float ek[DN];
    float m = 0.f;
#pragma unroll
    for (int k = 0; k < DN; ++k) {
      float t2 = step * (float)k - y;
      ek[k] = __expf(-t2 * t2 * inv2);
      m = fmaxf(m, ek[k]);
    }
    if (m > 0.f) {
      float im = 1.0f / m;
#pragma unroll
      for (int k = 0; k < DN; ++k) s[k] += ek[k] * im;
    }
  }
#pragma unroll
  for (int k = 0; k < DN; ++k) s[k] += __shfl_xor(s[k], 1);
  float smax = 0.f;
#pragma unroll
  for (int k = 0; k < DN; ++k) smax = fmaxf(smax, s[k]);
  float ism = (smax > 0.f) ? 1.0f / smax : 1.0f;

#pragma unroll
  for (int k = 0; k < 10; ++k) {
    float dv = s[half * 10 + k] * ism;
    dls[nl][half * 10 + k] = dv;
    if (n < n_node) dmat[(size_t)n * DN + half * 10 + k] = dv;
  }
  __syncthreads();

  // per-block moment partials, TRANSPOSED layout momp[u][block]
  for (int u = tid; u < 230; u += TB1) {
    float acc = 0.f;
    if (u < 210) {
      int a = 0, rem = u;
      while (rem >= DN - a) { rem -= DN - a; ++a; }
      int b = a + rem;
      for (int l = 0; l < 64; ++l) acc += dls[l][a] * dls[l][b];
    } else {
      int a = u - 210;
      for (int l = 0; l < 64; ++l) acc += dls[l][a];
    }
    momp[(size_t)u * NBW + blockIdx.x] = acc;
  }
}

// ---------- K2: reduce moment partials (coalesced) + BN stats ----------
__global__ __launch_bounds__(512) void k_coef(const float* __restrict__ momp, int nbd,
                                              const float* __restrict__ convw,
                                              const float* __restrict__ convb,
                                              const float* __restrict__ gamma,
                                              const float* __restrict__ beta,
                                              float* __restrict__ acoef,
                                              float* __restrict__ coefc, int n_node) {
  int c = blockIdx.x;
  int tid = threadIdx.x;
  __shared__ float P[DN * DN];
  __shared__ float S[DN];
  __shared__ float red1[512], red2[512];
  if (tid < 230) {
    float acc = 0.f;
    const float4* row4 = (const float4*)(momp + (size_t)tid * NBW);
    int nb4 = nbd >> 2;
    for (int b = 0; b < nb4; ++b) {
      float4 t = row4[b];
      acc += t.x + t.y + t.z + t.w;
    }
    for (int b = nb4 << 2; b < nbd; ++b) acc += momp[(size_t)tid * NBW + b];
    if (tid < 210) {
      int a = 0, rem = tid;
      while (rem >= DN - a) { rem -= DN - a; ++a; }
      int b = a + rem;
      P[a * DN + b] = acc; P[b * DN + a] = acc;
    } else {
      S[tid - 210] = acc;
    }
  }
  __syncthreads();

  float w[3][3];
#pragma unroll
  for (int p = 0; p < 3; ++p)
#pragma unroll
    for (int q = 0; q < 3; ++q) w[p][q] = convw[c * 9 + p * 3 + q];
  float b_c = convb[c];

  float ssq = 0.f, sm = 0.f;
  if (tid < DN * DN) {
    int i = tid / DN, j = tid % DN;
    bool iv[3] = { i > 0, true, i < DN - 1 };
    bool jv[3] = { j > 0, true, j < DN - 1 };
    int idxs[6]; float cf[6]; int nt = 0;
#pragma unroll
    for (int p = 0; p < 3; ++p) if (iv[p]) {
      float cc = 0.f;
#pragma unroll
      for (int q = 0; q < 3; ++q) if (jv[q]) cc += w[p][q];
      idxs[nt] = i - 1 + p; cf[nt] = cc; ++nt;
    }
#pragma unroll
    for (int q = 0; q < 3; ++q) if (jv[q]) {
      float cc = 0.f;
#pragma unroll
      for (int p = 0; p < 3; ++p) if (iv[p]) cc += w[p][q];
      idxs[nt] = j - 1 + q; cf[nt] = cc; ++nt;
    }
    float q1 = 0.f, q2 = 0.f;
    for (int u = 0; u < nt; ++u) {
      q2 += cf[u] * S[idxs[u]];
      for (int v2 = 0; v2 < nt; ++v2)
        q1 += cf[u] * cf[v2] * P[idxs[u] * DN + idxs[v2]];
    }
    ssq = q1 + 2.f * b_c * q2;
    sm = q2;
  }
  red1[tid] = ssq; red2[tid] = sm;
  __syncthreads();
  for (int st = 256; st > 0; st >>= 1) {
    if (tid < st) { red1[tid] += red1[tid + st]; red2[tid] += red2[tid + st]; }
    __syncthreads();
  }
  if (tid == 0) {
    float Nt = (float)n_node * 400.f;
    float S1 = red2[0] + Nt * b_c;
    float S2 = red1[0] + Nt * b_c * b_c;
    float mu = S1 / Nt;
    float var = S2 / Nt - mu * mu;
    float a = gamma[c] / sqrtf(var + 1e-5f);
    acoef[c] = a;
    coefc[c] = a * (b_c - mu) + beta[c];
  }
}

// ---------- K3: collapse conv+BN+FC1 weights — single-pass, float4, LDS-staged ----------
// Row stats from registers (class trick: first/mid/last); rows staged to LDS
// (stride 21 -> <=2-way bank conflict); col stats read LDS. w1 read exactly once.
__global__ __launch_bounds__(512) void k_buildU(const float* __restrict__ w1,
                                                const float* __restrict__ b1,
                                                const float* __restrict__ acoef,
                                                const float* __restrict__ coefc,
                                                const float* __restrict__ wq,
                                                const float* __restrict__ wp,
                                                float* __restrict__ U,
                                                float* __restrict__ Cst) {
  int o = blockIdx.x;
  int tid = threadIdx.x;
  __shared__ float sW[OCH * DN * 21];                 // 53.76 KB
  __shared__ float rowRS[OCH][DN], colCS[OCH][DN];
  __shared__ float rowRW[3][OCH][DN], colCW[3][OCH][DN];
  __shared__ float swq[288], swp[288], sac[OCH], scc[OCH], red[OCH];
  for (int idx = tid; idx < 288; idx += 512) { swq[idx] = wq[idx]; swp[idx] = wp[idx]; }
  if (tid < OCH) { sac[tid] = acoef[tid]; scc[tid] = coefc[tid]; }
  __syncthreads();

  const float* wbase = w1 + (size_t)o * (OCH * DN * DN);

  // pass A: load rows as float4, row stats from regs, stage into LDS
  for (int pair = tid; pair < OCH * DN; pair += 512) {
    int c = pair / DN, i = pair - c * DN;
    const float4* r = (const float4*)(wbase + pair * DN);
    float4 v0 = r[0], v1 = r[1], v2 = r[2], v3 = r[3], v4 = r[4];
    float first = v0.x, last = v4.w;
    float rs = v0.x + v0.y + v0.z + v0.w + v1.x + v1.y + v1.z + v1.w +
               v2.x + v2.y + v2.z + v2.w + v3.x + v3.y + v3.z + v3.w +
               v4.x + v4.y + v4.z + v4.w;
    float mid = rs - first - last;
#pragma unroll
    for (int p = 0; p < 3; ++p)
      rowRW[p][c][i] = first * swq[(c * 3 + p) * 3 + 0] +
                       mid   * swq[(c * 3 + p) * 3 + 1] +
                       last  * swq[(c * 3 + p) * 3 + 2];
    rowRS[c][i] = rs;
    float* dst = &sW[pair * 21];
    dst[0] = v0.x; dst[1] = v0.y; dst[2] = v0.z; dst[3] = v0.w;
    dst[4] = v1.x; dst[5] = v1.y; dst[6] = v1.z; dst[7] = v1.w;
    dst[8] = v2.x; dst[9] = v2.y; dst[10] = v2.z; dst[11] = v2.w;
    dst[12] = v3.x; dst[13] = v3.y; dst[14] = v3.z; dst[15] = v3.w;
    dst[16] = v4.x; dst[17] = v4.y; dst[18] = v4.z; dst[19] = v4.w;
  }
  __syncthreads();

  // pass B: col stats from LDS
  for (int pair = tid; pair < OCH * DN; pair += 512) {
    int c = pair / DN, j = pair - c * DN;
    const float* src = &sW[c * DN * 21 + j];
    float cs = 0.f, first = 0.f, last = 0.f;
#pragma unroll
    for (int i = 0; i < DN; ++i) {
      float vv = src[i * 21];
      cs += vv;
      if (i == 0) first = vv;
      if (i == DN - 1) last = vv;
    }
    float mid = cs - first - last;
#pragma unroll
    for (int q = 0; q < 3; ++q)
      colCW[q][c][j] = first * swp[(c * 3 + q) * 3 + 0] +
                       mid   * swp[(c * 3 + q) * 3 + 1] +
                       last  * swp[(c * 3 + q) * 3 + 2];
    colCS[c][j] = cs;
  }
  __syncthreads();

  if (tid < DN) {
    int a = tid;
    float u = 0.f;
#pragma unroll
    for (int c = 0; c < OCH; ++c) {
      float plain = rowRS[c][a] + colCS[c][a];
      float m = rowRW[1][c][a] + colCW[1][c][a];
      if (a < DN - 1) m += rowRW[0][c][a + 1] + colCW[0][c][a + 1];
      if (a > 0)      m += rowRW[2][c][a - 1] + colCW[2][c][a - 1];
      u += plain + sac[c] * m;
    }
    U[o * DN + a] = u;
  } else if (tid >= 64 && tid < 64 + OCH) {
    int c = tid - 64;
    float s = 0.f;
#pragma unroll
    for (int i = 0; i < DN; ++i) s += rowRS[c][i];
    red[c] = scc[c] * s;
  }
  __syncthreads();
  if (tid == 0) {
    float s = 0.f;
#pragma unroll
    for (int c = 0; c < OCH; ++c) s += red[c];
    Cst[o] = b1[o] + s;
  }
}

// ---------- K4: fused FC1(rank-20)+ReLU+FC2, node-quad phase-2 ----------
#define NTN 16
__global__ __launch_bounds__(256, 4) void k_final(const float* __restrict__ dmat,
                                                  const float* __restrict__ U,
                                                  const float* __restrict__ Cst,
                                                  const float* __restrict__ w2t,
                                                  const float* __restrict__ b2,
                                                  float* __restrict__ out, int n_node) {
  __shared__ float h1s[H1][20];        // 40 KB
  __shared__ float pacc[4][NTN][64];   // 16 KB
  int tid = threadIdx.x;
  int n0 = blockIdx.x * NTN;

  // ---- phase 1: h1s[k][node] = relu(Cst[k] + U[k]·d) ----
  {
    int node = tid & 15, kq = tid >> 4;
    float d0[DN];
#pragma unroll
    for (int a = 0; a < DN; ++a) d0[a] = 0.f;
    if (n0 + node < n_node) {
      const float4* dr = (const float4*)(dmat + (size_t)(n0 + node) * DN);
#pragma unroll
      for (int q = 0; q < 5; ++q) {
        float4 t = dr[q];
        d0[q * 4 + 0] = t.x; d0[q * 4 + 1] = t.y;
        d0[q * 4 + 2] = t.z; d0[q * 4 + 3] = t.w;
      }
    }
    for (int k = kq; k < H1; k += 16) {
      const float4* ur = (const float4*)(U + (size_t)k * DN);
      float z = Cst[k];
#pragma unroll
      for (int q = 0; q < 5; ++q) {
        float4 u4 = ur[q];
        z += u4.x * d0[q * 4 + 0] + u4.y * d0[q * 4 + 1] +
             u4.z * d0[q * 4 + 2] + u4.w * d0[q * 4 + 3];
      }
      h1s[k][node] = fmaxf(z, 0.f);
    }
  }
  __syncthreads();

  // ---- phase 2 ----
  {
    int w = tid >> 6;
    int lane = tid & 63;
    int q = lane >> 4;          // node quad
    int og = lane & 15;         // outs og*4..og*4+3
    float a0x = 0.f, a0y = 0.f, a0z = 0.f, a0w = 0.f;
    float a1x = 0.f, a1y = 0.f, a1z = 0.f, a1w = 0.f;
    float a2x = 0.f, a2y = 0.f, a2z = 0.f, a2w = 0.f;
    float a3x = 0.f, a3y = 0.f, a3z = 0.f, a3w = 0.f;
    int k0 = w * 125, k1 = k0 + 125;
    for (int k = k0; k < k1; ++k) {
      float4 hv = *(const float4*)&h1s[k][q * 4];
      float4 wv = *(const float4*)(w2t + (size_t)k * 64 + og * 4);
      a0x += hv.x * wv.x; a0y += hv.x * wv.y; a0z += hv.x * wv.z; a0w += hv.x * wv.w;
      a1x += hv.y * wv.x; a1y += hv.y * wv.y; a1z += hv.y * wv.z; a1w += hv.y * wv.w;
      a2x += hv.z * wv.x; a2y += hv.z * wv.y; a2z += hv.z * wv.z; a2w += hv.z * wv.w;
      a3x += hv.w * wv.x; a3y += hv.w * wv.y; a3z += hv.w * wv.z; a3w += hv.w * wv.w;
    }
    *(float4*)&pacc[w][q * 4 + 0][og * 4] = make_float4(a0x, a0y, a0z, a0w);
    *(float4*)&pacc[w][q * 4 + 1][og * 4] = make_float4(a1x, a1y, a1z, a1w);
    *(float4*)&pacc[w][q * 4 + 2][og * 4] = make_float4(a2x, a2y, a2z, a2w);
    *(float4*)&pacc[w][q * 4 + 3][og * 4] = make_float4(a3x, a3y, a3z, a3w);
  }
  __syncthreads();

  for (int idx = tid; idx < NTN * H2; idx += 256) {
    int n = idx / H2, o = idx - n * H2;
    float vv = pacc[0][n][o] + pacc[1][n][o] + pacc[2][n][o] + pacc[3][n][o] + b2[o];
    if (n0 + n < n_node) out[(size_t)(n0 + n) * H2 + o] = vv;
  }
}

extern "C" void kernel_launch(void* const* d_in, const int* in_sizes, int n_in,
                              void* d_out, int out_size, void* d_ws, size_t ws_size,
                              hipStream_t stream) {
  const float* oe    = (const float*)d_in[0];
  const int*   nei   = (const int*)d_in[1];
  const int*   eai   = (const int*)d_in[2];
  const float* convw = (const float*)d_in[3];
  const float* convb = (const float*)d_in[4];
  const float* gamma = (const float*)d_in[5];
  const float* beta  = (const float*)d_in[6];
  const float* w1    = (const float*)d_in[7];
  const float* b1    = (const float*)d_in[8];
  const float* w2    = (const float*)d_in[9];
  const float* b2    = (const float*)d_in[10];
  float* out = (float*)d_out;
  float* ws  = (float*)d_ws;

  int n_node = in_sizes[2] / 2;

  float* dmat  = ws + OFF_D;
  float* momp  = ws + OFF_MOMP;
  float* acoef = ws + OFF_ACOEF;
  float* coefc = ws + OFF_COEFC;
  float* wq    = ws + OFF_WQ;
  float* wp    = ws + OFF_WP;
  float* U     = ws + OFF_U;
  float* Cst   = ws + OFF_CST;
  float* w2t   = ws + OFF_W2T;

  int nbd = (n_node + 63) / 64;
  k_gd<<<nbd + 33, TB1, 0, stream>>>(oe, nei, eai, w2, convw,
                                     dmat, momp, w2t, wq, wp, n_node);
  k_coef<<<OCH, 512, 0, stream>>>(momp, nbd, convw, convb, gamma, beta,
                                  acoef, coefc, n_node);
  k_buildU<<<H1, 512, 0, stream>>>(w1, b1, acoef, coefc, wq, wp, U, Cst);
  k_final<<<(n_node + NTN - 1) / NTN, 256, 0, stream>>>(dmat, U, Cst, w2t, b2, out, n_node);
}

// Round 11
// 55.146 us; speedup vs baseline: 2.8669x; 1.2439x over previous
//
#include <hip/hip_runtime.h>
#include <hip/hip_bf16.h>
#include <math.h>

#define NFEAT 17
#define DN 20
#define OCH 32
#define H1 500
#define H2 60

// Only d[0..3] are nonzero: g-rows are unit-norm positive => y=h[f] <= 2 < grid
// step 2.632*2; max-normalized Gaussian at k>=4 from y<=2 underflows fp32 to 0
// (k=2,3 are retained in the compact float4).
#define DK 4

// ws float offsets
#define OFF_D      0         // 8192*4 = 32768 (compact dmat [n][4])
#define OFF_MOMP   32768     // 14 * NBW = 3584 (transposed [u][block])
#define OFF_ACOEF  36352     // 32
#define OFF_COEFC  36384     // 32
#define OFF_WQ     36416     // 288
#define OFF_WP     36704     // 288
#define OFF_U4     36992     // 500*4 = 2000 (compact U)
#define OFF_CST    38992     // 512
#define OFF_W2T    39504     // 500*64 (padded w2 transpose [o][64])

#define NBW 256  // momp block-stride (capacity)

// ---------- K1: fused g-gather + distribute(4-pt) + per-block moment partials ----------
// 2 threads per node. Tail blocks: 8x LDS-tiled w2 transpose + 1x wq/wp tables.
#define TB1 128
__global__ __launch_bounds__(TB1) void k_gd(const float* __restrict__ oe,
                                            const int* __restrict__ nei,
                                            const int* __restrict__ eai,
                                            const float* __restrict__ w2,
                                            const float* __restrict__ convw,
                                            float* __restrict__ dmat,
                                            float* __restrict__ momp,
                                            float* __restrict__ w2t,
                                            float* __restrict__ wq,
                                            float* __restrict__ wp, int n_node) {
  int nbd = (n_node + 63) / 64;
  int tid = threadIdx.x;
  if ((int)blockIdx.x >= nbd) {
    int tb = blockIdx.x - nbd;
    if (tb < 8) {
      // coalesced transpose of one 64-col slab: w2[60][500] -> w2t[500][64]
      __shared__ float sT[64][61];
      int o0 = tb * 64;
      int lo = tid & 63, j2 = tid >> 6;
      for (int j = j2; j < H2; j += 2)
        if (o0 + lo < H1) sT[lo][j] = w2[(size_t)j * H1 + o0 + lo];
      __syncthreads();
      int jj = tid & 63, o2 = tid >> 6;
      for (int ol = o2; ol < 64; ol += 2) {
        int o = o0 + ol;
        if (o < H1) w2t[(size_t)o * 64 + jj] = (jj < H2) ? sT[ol][jj] : 0.f;
      }
    } else if (tid < OCH) {
      int c = tid;
      float w[3][3];
#pragma unroll
      for (int p = 0; p < 3; ++p)
#pragma unroll
        for (int q = 0; q < 3; ++q) w[p][q] = convw[c * 9 + p * 3 + q];
#pragma unroll
      for (int p = 0; p < 3; ++p) {
        wq[(c * 3 + p) * 3 + 0] = w[p][1] + w[p][2];
        wq[(c * 3 + p) * 3 + 1] = w[p][0] + w[p][1] + w[p][2];
        wq[(c * 3 + p) * 3 + 2] = w[p][0] + w[p][1];
      }
#pragma unroll
      for (int q = 0; q < 3; ++q) {
        wp[(c * 3 + q) * 3 + 0] = w[1][q] + w[2][q];
        wp[(c * 3 + q) * 3 + 1] = w[0][q] + w[1][q] + w[2][q];
        wp[(c * 3 + q) * 3 + 2] = w[0][q] + w[1][q];
      }
    }
    return;
  }

  __shared__ float dls[64][5];
  int nl = tid >> 1, half = tid & 1;
  int n = blockIdx.x * 64 + nl;

  float v[NFEAT];
#pragma unroll
  for (int f = 0; f < NFEAT; ++f) v[f] = 0.f;
  if (n < n_node) {
    int e = eai[(size_t)n * 2 + half];
    float a4[NFEAT];
#pragma unroll
    for (int f = 0; f < NFEAT; ++f) a4[f] = 0.f;
#pragma unroll
    for (int m = 0; m < 4; ++m) {
      int at = nei[(size_t)e * 4 + m];
      const float* row = oe + (size_t)at * NFEAT;
#pragma unroll
      for (int f = 0; f < NFEAT; ++f) a4[f] += row[f];
    }
    float nrm = 0.f;
#pragma unroll
    for (int f = 0; f < NFEAT; ++f) { float t = a4[f] * 0.25f; a4[f] = t; nrm += t * t; }
    float inv = 1.0f / sqrtf(nrm);
#pragma unroll
    for (int f = 0; f < NFEAT; ++f) v[f] = a4[f] * inv;
  }
  float h[NFEAT];
#pragma unroll
  for (int f = 0; f < NFEAT; ++f) h[f] = v[f] + __shfl_xor(v[f], 1);

  const float step = 50.0f / 19.0f;
  const float inv2 = 1.0f / (2.0f * 0.3f * 0.3f);
  float s0 = 0.f, s1 = 0.f, s2 = 0.f, s3 = 0.f;
  int f0 = half ? 9 : 0, f1 = half ? NFEAT : 9;
  for (int f = f0; f < f1; ++f) {
    float y = h[f];
    if (!(y > 0.0f && y < 110.0f)) continue;
    float t0 = -y, t1 = step - y, t2 = 2.f * step - y, t3 = 3.f * step - y;
    float e0 = __expf(-t0 * t0 * inv2);
    float e1 = __expf(-t1 * t1 * inv2);
    float e2 = __expf(-t2 * t2 * inv2);
    float e3 = __expf(-t3 * t3 * inv2);
    float m = fmaxf(fmaxf(e0, e1), fmaxf(e2, e3));
    if (m > 0.f) {
      float im = 1.0f / m;
      s0 += e0 * im; s1 += e1 * im; s2 += e2 * im; s3 += e3 * im;
    }
  }
  s0 += __shfl_xor(s0, 1); s1 += __shfl_xor(s1, 1);
  s2 += __shfl_xor(s2, 1); s3 += __shfl_xor(s3, 1);
  float smax = fmaxf(fmaxf(s0, s1), fmaxf(s2, s3));
  float ism = (smax > 0.f) ? 1.0f / smax : 1.0f;
  float d0 = s0 * ism, d1 = s1 * ism, d2 = s2 * ism, d3 = s3 * ism;

  if (half == 0) {
    dls[nl][0] = d0; dls[nl][1] = d1; dls[nl][2] = d2; dls[nl][3] = d3;
    if (n < n_node)
      *(float4*)(dmat + (size_t)n * DK) = make_float4(d0, d1, d2, d3);
  }
  __syncthreads();

  // per-block moment partials: 10 tri P(4x4) + 4 sums, transposed momp[u][block]
  if (tid < 14) {
    int u = tid;
    float acc = 0.f;
    if (u < 10) {
      int a = 0, rem = u;
      while (rem >= DK - a) { rem -= DK - a; ++a; }
      int b = a + rem;
      for (int l = 0; l < 64; ++l) acc += dls[l][a] * dls[l][b];
    } else {
      int a = u - 10;
      for (int l = 0; l < 64; ++l) acc += dls[l][a];
    }
    momp[(size_t)u * NBW + blockIdx.x] = acc;
  }
}

// ---------- K2: reduce 14 moment partials (coalesced) + BN stats ----------
__global__ __launch_bounds__(512) void k_coef(const float* __restrict__ momp, int nbd,
                                              const float* __restrict__ convw,
                                              const float* __restrict__ convb,
                                              const float* __restrict__ gamma,
                                              const float* __restrict__ beta,
                                              float* __restrict__ acoef,
                                              float* __restrict__ coefc, int n_node) {
  int c = blockIdx.x;
  int tid = threadIdx.x;
  __shared__ float P[DN * DN];
  __shared__ float S[DN];
  __shared__ float red1[512], red2[512];
  if (tid < DN * DN) P[tid] = 0.f;
  if (tid >= 448 && tid < 448 + DN) S[tid - 448] = 0.f;
  __syncthreads();
  if (tid < 14) {
    float acc = 0.f;
    const float4* row4 = (const float4*)(momp + (size_t)tid * NBW);
    int nb4 = nbd >> 2;
    for (int b = 0; b < nb4; ++b) {
      float4 t = row4[b];
      acc += t.x + t.y + t.z + t.w;
    }
    for (int b = nb4 << 2; b < nbd; ++b) acc += momp[(size_t)tid * NBW + b];
    if (tid < 10) {
      int a = 0, rem = tid;
      while (rem >= DK - a) { rem -= DK - a; ++a; }
      int b = a + rem;
      P[a * DN + b] = acc; P[b * DN + a] = acc;
    } else {
      S[tid - 10] = acc;
    }
  }
  __syncthreads();

  float w[3][3];
#pragma unroll
  for (int p = 0; p < 3; ++p)
#pragma unroll
    for (int q = 0; q < 3; ++q) w[p][q] = convw[c * 9 + p * 3 + q];
  float b_c = convb[c];

  float ssq = 0.f, sm = 0.f;
  if (tid < DN * DN) {
    int i = tid / DN, j = tid % DN;
    bool iv[3] = { i > 0, true, i < DN - 1 };
    bool jv[3] = { j > 0, true, j < DN - 1 };
    int idxs[6]; float cf[6]; int nt = 0;
#pragma unroll
    for (int p = 0; p < 3; ++p) if (iv[p]) {
      float cc = 0.f;
#pragma unroll
      for (int q = 0; q < 3; ++q) if (jv[q]) cc += w[p][q];
      idxs[nt] = i - 1 + p; cf[nt] = cc; ++nt;
    }
#pragma unroll
    for (int q = 0; q < 3; ++q) if (jv[q]) {
      float cc = 0.f;
#pragma unroll
      for (int p = 0; p < 3; ++p) if (iv[p]) cc += w[p][q];
      idxs[nt] = j - 1 + q; cf[nt] = cc; ++nt;
    }
    float q1 = 0.f, q2 = 0.f;
    for (int u = 0; u < nt; ++u) {
      q2 += cf[u] * S[idxs[u]];
      for (int v2 = 0; v2 < nt; ++v2)
        q1 += cf[u] * cf[v2] * P[idxs[u] * DN + idxs[v2]];
    }
    ssq = q1 + 2.f * b_c * q2;
    sm = q2;
  }
  red1[tid] = ssq; red2[tid] = sm;
  __syncthreads();
  for (int st = 256; st > 0; st >>= 1) {
    if (tid < st) { red1[tid] += red1[tid + st]; red2[tid] += red2[tid + st]; }
    __syncthreads();
  }
  if (tid == 0) {
    float Nt = (float)n_node * 400.f;
    float S1 = red2[0] + Nt * b_c;
    float S2 = red1[0] + Nt * b_c * b_c;
    float mu = S1 / Nt;
    float var = S2 / Nt - mu * mu;
    float a = gamma[c] / sqrtf(var + 1e-5f);
    acoef[c] = a;
    coefc[c] = a * (b_c - mu) + beta[c];
  }
}

// ---------- K3: collapse conv+BN+FC1 weights — single-pass, compact U4 output ----------
__global__ __launch_bounds__(512) void k_buildU(const float* __restrict__ w1,
                                                const float* __restrict__ b1,
                                                const float* __restrict__ acoef,
                                                const float* __restrict__ coefc,
                                                const float* __restrict__ wq,
                                                const float* __restrict__ wp,
                                                float* __restrict__ U4,
                                                float* __restrict__ Cst) {
  int o = blockIdx.x;
  int tid = threadIdx.x;
  __shared__ float sW[OCH * DN * 21];                 // 53.76 KB
  __shared__ float rowRS[OCH][DN], colCS[OCH][DN];
  __shared__ float rowRW[3][OCH][DN], colCW[3][OCH][DN];
  __shared__ float swq[288], swp[288], sac[OCH], scc[OCH], red[OCH];
  for (int idx = tid; idx < 288; idx += 512) { swq[idx] = wq[idx]; swp[idx] = wp[idx]; }
  if (tid < OCH) { sac[tid] = acoef[tid]; scc[tid] = coefc[tid]; }
  __syncthreads();

  const float* wbase = w1 + (size_t)o * (OCH * DN * DN);

  // pass A: float4 row loads, row stats from regs, stage to LDS (stride 21)
  for (int pair = tid; pair < OCH * DN; pair += 512) {
    int c = pair / DN, i = pair - c * DN;
    const float4* r = (const float4*)(wbase + pair * DN);
    float4 v0 = r[0], v1 = r[1], v2 = r[2], v3 = r[3], v4 = r[4];
    float first = v0.x, last = v4.w;
    float rs = v0.x + v0.y + v0.z + v0.w + v1.x + v1.y + v1.z + v1.w +
               v2.x + v2.y + v2.z + v2.w + v3.x + v3.y + v3.z + v3.w +
               v4.x + v4.y + v4.z + v4.w;
    float mid = rs - first - last;
#pragma unroll
    for (int p = 0; p < 3; ++p)
      rowRW[p][c][i] = first * swq[(c * 3 + p) * 3 + 0] +
                       mid   * swq[(c * 3 + p) * 3 + 1] +
                       last  * swq[(c * 3 + p) * 3 + 2];
    rowRS[c][i] = rs;
    float* dst = &sW[pair * 21];
    dst[0] = v0.x; dst[1] = v0.y; dst[2] = v0.z; dst[3] = v0.w;
    dst[4] = v1.x; dst[5] = v1.y; dst[6] = v1.z; dst[7] = v1.w;
    dst[8] = v2.x; dst[9] = v2.y; dst[10] = v2.z; dst[11] = v2.w;
    dst[12] = v3.x; dst[13] = v3.y; dst[14] = v3.z; dst[15] = v3.w;
    dst[16] = v4.x; dst[17] = v4.y; dst[18] = v4.z; dst[19] = v4.w;
  }
  __syncthreads();

  // pass B: col stats from LDS
  for (int pair = tid; pair < OCH * DN; pair += 512) {
    int c = pair / DN, j = pair - c * DN;
    const float* src = &sW[c * DN * 21 + j];
    float cs = 0.f, first = 0.f, last = 0.f;
#pragma unroll
    for (int i = 0; i < DN; ++i) {
      float vv = src[i * 21];
      cs += vv;
      if (i == 0) first = vv;
      if (i == DN - 1) last = vv;
    }
    float mid = cs - first - last;
#pragma unroll
    for (int q = 0; q < 3; ++q)
      colCW[q][c][j] = first * swp[(c * 3 + q) * 3 + 0] +
                       mid   * swp[(c * 3 + q) * 3 + 1] +
                       last  * swp[(c * 3 + q) * 3 + 2];
    colCS[c][j] = cs;
  }
  __syncthreads();

  if (tid < DK) {   // only a=0..3 matter downstream (d[a>=4]==0)
    int a = tid;
    float u = 0.f;
#pragma unroll
    for (int c = 0; c < OCH; ++c) {
      float plain = rowRS[c][a] + colCS[c][a];
      float m = rowRW[1][c][a] + colCW[1][c][a];
      m += rowRW[0][c][a + 1] + colCW[0][c][a + 1];
      if (a > 0) m += rowRW[2][c][a - 1] + colCW[2][c][a - 1];
      u += plain + sac[c] * m;
    }
    U4[o * DK + a] = u;
  } else if (tid >= 64 && tid < 64 + OCH) {
    int c = tid - 64;
    float s = 0.f;
#pragma unroll
    for (int i = 0; i < DN; ++i) s += rowRS[c][i];
    red[c] = scc[c] * s;
  }
  __syncthreads();
  if (tid == 0) {
    float s = 0.f;
#pragma unroll
    for (int c = 0; c < OCH; ++c) s += red[c];
    Cst[o] = b1[o] + s;
  }
}

// ---------- K4: fused FC1(rank-4)+ReLU+FC2, node-quad phase-2 ----------
#define NTN 16
__global__ __launch_bounds__(256, 4) void k_final(const float* __restrict__ dmat,
                                                  const float* __restrict__ U4,
                                                  const float* __restrict__ Cst,
                                                  const float* __restrict__ w2t,
                                                  const float* __restrict__ b2,
                                                  float* __restrict__ out, int n_node) {
  __shared__ float h1s[H1][20];        // 40 KB (cols 0..15 used)
  __shared__ float pacc[4][NTN][64];   // 16 KB
  int tid = threadIdx.x;
  int n0 = blockIdx.x * NTN;

  // ---- phase 1: h1s[k][node] = relu(Cst[k] + U4[k]·d4) ----
  {
    int node = tid & 15, kq = tid >> 4;
    float4 d4 = make_float4(0.f, 0.f, 0.f, 0.f);
    if (n0 + node < n_node)
      d4 = *(const float4*)(dmat + (size_t)(n0 + node) * DK);
    for (int k = kq; k < H1; k += 16) {
      float4 u4 = *(const float4*)(U4 + (size_t)k * DK);
      float z = Cst[k] + u4.x * d4.x + u4.y * d4.y + u4.z * d4.z + u4.w * d4.w;
      h1s[k][node] = fmaxf(z, 0.f);
    }
  }
  __syncthreads();

  // ---- phase 2 ----
  {
    int w = tid >> 6;
    int lane = tid & 63;
    int q = lane >> 4;          // node quad
    int og = lane & 15;         // outs og*4..og*4+3
    float a0x = 0.f, a0y = 0.f, a0z = 0.f, a0w = 0.f;
    float a1x = 0.f, a1y = 0.f, a1z = 0.f, a1w = 0.f;
    float a2x = 0.f, a2y = 0.f, a2z = 0.f, a2w = 0.f;
    float a3x = 0.f, a3y = 0.f, a3z = 0.f, a3w = 0.f;
    int k0 = w * 125, k1 = k0 + 125;
    for (int k = k0; k < k1; ++k) {
      float4 hv = *(const float4*)&h1s[k][q * 4];
      float4 wv = *(const float4*)(w2t + (size_t)k * 64 + og * 4);
      a0x += hv.x * wv.x; a0y += hv.x * wv.y; a0z += hv.x * wv.z; a0w += hv.x * wv.w;
      a1x += hv.y * wv.x; a1y += hv.y * wv.y; a1z += hv.y * wv.z; a1w += hv.y * wv.w;
      a2x += hv.z * wv.x; a2y += hv.z * wv.y; a2z += hv.z * wv.z; a2w += hv.z * wv.w;
      a3x += hv.w * wv.x; a3y += hv.w * wv.y; a3z += hv.w * wv.z; a3w += hv.w * wv.w;
    }
    *(float4*)&pacc[w][q * 4 + 0][og * 4] = make_float4(a0x, a0y, a0z, a0w);
    *(float4*)&pacc[w][q * 4 + 1][og * 4] = make_float4(a1x, a1y, a1z, a1w);
    *(float4*)&pacc[w][q * 4 + 2][og * 4] = make_float4(a2x, a2y, a2z, a2w);
    *(float4*)&pacc[w][q * 4 + 3][og * 4] = make_float4(a3x, a3y, a3z, a3w);
  }
  __syncthreads();

  for (int idx = tid; idx < NTN * H2; idx += 256) {
    int n = idx / H2, o = idx - n * H2;
    float vv = pacc[0][n][o] + pacc[1][n][o] + pacc[2][n][o] + pacc[3][n][o] + b2[o];
    if (n0 + n < n_node) out[(size_t)(n0 + n) * H2 + o] = vv;
  }
}

extern "C" void kernel_launch(void* const* d_in, const int* in_sizes, int n_in,
                              void* d_out, int out_size, void* d_ws, size_t ws_size,
                              hipStream_t stream) {
  const float* oe    = (const float*)d_in[0];
  const int*   nei   = (const int*)d_in[1];
  const int*   eai   = (const int*)d_in[2];
  const float* convw = (const float*)d_in[3];
  const float* convb = (const float*)d_in[4];
  const float* gamma = (const float*)d_in[5];
  const float* beta  = (const float*)d_in[6];
  const float* w1    = (const float*)d_in[7];
  const float* b1    = (const float*)d_in[8];
  const float* w2    = (const float*)d_in[9];
  const float* b2    = (const float*)d_in[10];
  float* out = (float*)d_out;
  float* ws  = (float*)d_ws;

  int n_node = in_sizes[2] / 2;

  float* dmat  = ws + OFF_D;
  float* momp  = ws + OFF_MOMP;
  float* acoef = ws + OFF_ACOEF;
  float* coefc = ws + OFF_COEFC;
  float* wq    = ws + OFF_WQ;
  float* wp    = ws + OFF_WP;
  float* U4    = ws + OFF_U4;
  float* Cst   = ws + OFF_CST;
  float* w2t   = ws + OFF_W2T;

  int nbd = (n_node + 63) / 64;
  k_gd<<<nbd + 9, TB1, 0, stream>>>(oe, nei, eai, w2, convw,
                                    dmat, momp, w2t, wq, wp, n_node);
  k_coef<<<OCH, 512, 0, stream>>>(momp, nbd, convw, convb, gamma, beta,
                                  acoef, coefc, n_node);
  k_buildU<<<H1, 512, 0, stream>>>(w1, b1, acoef, coefc, wq, wp, U4, Cst);
  k_final<<<(n_node + NTN - 1) / NTN, 256, 0, stream>>>(dmat, U4, Cst, w2t, b2, out, n_node);
}